// Round 10
// baseline (177.407 us; speedup 1.0000x reference)
//
#include <hip/hip_runtime.h>
#include <hip/hip_bf16.h>

typedef __attribute__((ext_vector_type(8))) short short8;
typedef __attribute__((ext_vector_type(4))) float f32x4;
typedef __attribute__((ext_vector_type(16))) float f32x16;
typedef __attribute__((ext_vector_type(2))) unsigned int uint2v;
typedef __attribute__((ext_vector_type(4))) unsigned int uint4v;
typedef unsigned short u16;

#define MFMA_BF16(a, b, c) __builtin_amdgcn_mfma_f32_16x16x32_bf16(a, b, c, 0, 0, 0)
#define MFMA32(a, b, c) __builtin_amdgcn_mfma_f32_32x32x16_bf16(a, b, c, 0, 0, 0)

#define T_SEQ 2048
#define DMODEL 1024
#define NHEADS 16
#define DHEAD 64
#define NEG_BIG (-30000.0f)
#define QSCALE 0.1803368801111f  // 0.125 * log2(e): softmax in exp2 domain
#define RESCALE_THR 8.0f         // defer-max threshold (exp2 domain): P <= 2^8

#if __has_builtin(__builtin_amdgcn_exp2f)
#define EXP2(x) __builtin_amdgcn_exp2f(x)
#else
#define EXP2(x) exp2f(x)
#endif

__device__ __forceinline__ unsigned bfr(unsigned u) {
  return (u + 0x7fffu + ((u >> 16) & 1u)) >> 16;
}
__device__ __forceinline__ uint4v ld8bf(const float* __restrict__ p) {
  const uint4v a = *(const uint4v*)p;
  const uint4v b = *(const uint4v*)(p + 4);
  uint4v r;
  r[0] = bfr(a[0]) | (bfr(a[1]) << 16);
  r[1] = bfr(a[2]) | (bfr(a[3]) << 16);
  r[2] = bfr(b[0]) | (bfr(b[1]) << 16);
  r[3] = bfr(b[2]) | (bfr(b[3]) << 16);
  return r;
}
__device__ __forceinline__ u16 f2bf(float f) {
  unsigned u = __float_as_uint(f);
  u += 0x7fffu + ((u >> 16) & 1u);
  return (u16)(u >> 16);
}
// packed bf16 truncation (P in [0,2^8], rel err < 0.4%)
__device__ __forceinline__ unsigned pk2(float a, float b) {
  return (__float_as_uint(a) >> 16) | (__float_as_uint(b) & 0xffff0000u);
}
// async global->LDS DMA, 16B per lane; lds dest must be uniform-base + lane*16
__device__ __forceinline__ void gld16(const u16* g, u16* l) {
  __builtin_amdgcn_global_load_lds(
      (const __attribute__((address_space(1))) unsigned int*)g,
      (__attribute__((address_space(3))) unsigned int*)l, 16, 0, 0);
}

// ---------------------------------------------------------------- cvt fp32->bf16
__global__ __launch_bounds__(256) void cvt_all(
    const float* __restrict__ x, const float* __restrict__ wq,
    const float* __restrict__ wk, const float* __restrict__ wv,
    const float* __restrict__ wo, u16* __restrict__ xh, u16* __restrict__ wqh,
    u16* __restrict__ wkh, u16* __restrict__ wvh, u16* __restrict__ woh) {
  int bi = blockIdx.x;
  const float* s;
  u16* d;
  size_t base;
  if (bi < 2048) {
    s = x; d = xh; base = (size_t)bi * 2048;
  } else {
    int k = (bi - 2048) >> 9;
    int r = (bi - 2048) & 511;
    s = (k == 0) ? wq : (k == 1) ? wk : (k == 2) ? wv : wo;
    d = (k == 0) ? wqh : (k == 1) ? wkh : (k == 2) ? wvh : woh;
    base = (size_t)r * 2048;
  }
  size_t i = base + (size_t)threadIdx.x * 8;
  *(uint4v*)&d[i] = ld8bf(&s[i]);
}

// ---------------------------------------------------------------- QKV proj (bf16)
// 1-D grid 768, XCD-swizzled (id&7 = XCD, x-chunk of 4 innermost). z=0 Q
// (pre-scaled), z=1 K -> (b,h,t,d); z=2 V -> TRANSPOSED (b,h,d,t) via
// per-wave LDS transpose epilogue (128B-coalesced stores).
__global__ __launch_bounds__(256) void gemm_qkv(
    const u16* __restrict__ X, const u16* __restrict__ Wq,
    const u16* __restrict__ Wk, const u16* __restrict__ Wv,
    u16* __restrict__ Qo, u16* __restrict__ Ko, u16* __restrict__ Vo) {
  __shared__ __attribute__((aligned(16))) u16 sm[16384];  // A dbuf | B dbuf; reused as TT
  const int tid = threadIdx.x, lane = tid & 63, w = tid >> 6;
  const int wm = (w >> 1) * 64, wn = (w & 1) * 64;
  const int lrow = lane & 15;
  const int lk = (lane >> 4) << 3;
  const int lq = (lane >> 4) << 2;

  const int id = blockIdx.x;        // 0..767
  const int xcd = id & 7, r8 = id >> 3;   // r8: 0..95
  const int xo = r8 & 3, yz = r8 >> 2;    // yz: 0..23
  const int y = yz & 7, z = yz >> 3;      // y: 0..7, z: 0..2
  const int mBase = (xcd * 4 + xo) * 128, nBase = y * 128;

  const u16* Bt = (z == 0) ? Wq : (z == 1) ? Wk : Wv;
  u16* D = (z == 0) ? Qo : (z == 1) ? Ko : Vo;
  const float scale = (z == 0) ? QSCALE : 1.0f;

  f32x4 acc[4][4];
#pragma unroll
  for (int mi = 0; mi < 4; mi++)
#pragma unroll
    for (int ni = 0; ni < 4; ni++) acc[mi][ni] = (f32x4)0.0f;

  auto stage = [&](int buf, int k0) {
#pragma unroll
    for (int i = 0; i < 2; i++) {
      int c = i * 256 + tid;
      int r = c >> 2, kk = (c & 3) << 3;
      gld16(&X[(size_t)(mBase + r) * 1024 + k0 + kk], &sm[buf * 4096 + c * 8]);
      gld16(&Bt[(size_t)(nBase + r) * 1024 + k0 + kk],
            &sm[8192 + buf * 4096 + c * 8]);
    }
  };

  stage(0, 0);
  __syncthreads();
  int cur = 0;
  for (int k0 = 0; k0 < 1024; k0 += 32) {
    if (k0 + 32 < 1024) stage(cur ^ 1, k0 + 32);
    short8 af[4], bf[4];
#pragma unroll
    for (int mi = 0; mi < 4; mi++)
      af[mi] = *(const short8*)&sm[cur * 4096 + (wm + mi * 16 + lrow) * 32 + lk];
#pragma unroll
    for (int ni = 0; ni < 4; ni++)
      bf[ni] =
          *(const short8*)&sm[8192 + cur * 4096 + (wn + ni * 16 + lrow) * 32 + lk];
#pragma unroll
    for (int mi = 0; mi < 4; mi++)
#pragma unroll
      for (int ni = 0; ni < 4; ni++)
        acc[mi][ni] = MFMA_BF16(af[mi], bf[ni], acc[mi][ni]);
    __syncthreads();  // drains vmcnt (next tile landed) + lgkm
    cur ^= 1;
  }

  if (z != 2) {
#pragma unroll
    for (int mi = 0; mi < 4; mi++)
#pragma unroll
      for (int r = 0; r < 4; r++) {
        int m = mBase + wm + mi * 16 + lq + r;
        int b = m >> 11, t = m & 2047;
#pragma unroll
        for (int ni = 0; ni < 4; ni++) {
          int n = nBase + wn + ni * 16 + lrow;
          int h = n >> 6, dd = n & 63;
          D[(((size_t)(b * NHEADS + h)) * T_SEQ + t) * DHEAD + dd] =
              f2bf(acc[mi][ni][r] * scale);
        }
      }
  } else {
    // V: per-wave 64x64 transpose in LDS (granule-XOR swizzle), then
    // coalesced stores: 8 lanes x 16B = 128B contiguous along t per d-row.
    u16* TT = &sm[w * 4096];  // wave-private -> no barrier needed
#pragma unroll
    for (int mi = 0; mi < 4; mi++)
#pragma unroll
      for (int r = 0; r < 4; r++) {
        int t_loc = mi * 16 + lq + r;
#pragma unroll
        for (int ni = 0; ni < 4; ni++) {
          int d_loc = ni * 16 + lrow;
          TT[d_loc * 64 + ((((t_loc >> 3) ^ (d_loc & 7)) << 3) | (t_loc & 7))] =
              f2bf(acc[mi][ni][r]);
        }
      }
    const int b = (mBase + wm) >> 11;
    const int t0 = (mBase + wm) & 2047;
#pragma unroll
    for (int it = 0; it < 8; it++) {
      int d_loc = it * 8 + (lane >> 3);
      int ch = lane & 7;
      short8 v = *(const short8*)&TT[d_loc * 64 + ((ch ^ (d_loc & 7)) << 3)];
      int n = nBase + wn + d_loc;
      int h = n >> 6, dd = n & 63;
      *(uint4v*)&D[(((size_t)((b * NHEADS + h) * DHEAD + dd)) * T_SEQ) + t0 +
                   ch * 8] = *(const uint4v*)&v;
    }
  }
}

// ---------------------------------------------------------------- attention
// R10 = R9 structure with the R8-PROVEN shfl_xor(.,32) cross-lane ops
// restored (R9's permlane32_swap direction was unverified and wrong: actual
// HW swaps vdst.lo with vsrc.hi, making the softmax cross-half reduce a
// no-op -> absmax 3.04). Clean single-variable test of the occupancy lever:
// q-tile 64, 256 thr = 2 kv-parity groups x 2 waves, grid 1024 -> 4
// blocks/CU = 16 waves/CU (2x R8). Halved q-tile also halves LDS reads per
// kv-tile (2 readers not 4).
// LDS 32768B: K slots [0,16K) (slot=parity), V slots [16K,32K); single-
// buffered, 2 barriers/super-iter (exposed DMA hidden by 3 other blocks).
// Decode: id&7=XCD (4 bh each, L2-resident, FETCH~12MB); qt = seg*8 +/- qv
// -> co-resident quads {id,id+256,...} have const sum(qt)=62, same bh.
// Merge (2 partials, exact f32) in freed staging LDS; empty group's c1=0.
__global__ __launch_bounds__(256, 4) void attn_q64(
    const u16* __restrict__ Qg, const u16* __restrict__ Kg,
    const u16* __restrict__ Vtg, u16* __restrict__ Ob) {
  __shared__ __attribute__((aligned(16))) u16 smem[16384];  // 32768 B

  const int tid = threadIdx.x;
  const int w = tid >> 6, lane = tid & 63;
  const int g = w >> 1;             // kv-parity group 0/1
  const int wg = w & 1;             // q 32-slice within the 64-q tile
  const int l31 = lane & 31, h = lane >> 5;
  const int rsw = l31 & 7;          // swizzle key (= row&7)

  const int id = blockIdx.x;        // 0..1023
  const int seg = id >> 8;          // 0..3
  const int xcd = id & 7;
  const int bsub = (id >> 3) & 3;
  const int qv = (id >> 5) & 7;
  const int qt = (seg & 1) ? (seg * 8 + 7 - qv) : (seg * 8 + qv);
  const int bh = xcd * 4 + bsub;
  const int b = bh >> 4, hh = bh & 15;
  const int qb = qt << 6;
  const u16* Qp = Qg + (size_t)bh * T_SEQ * DHEAD;
  const u16* Kp = Kg + (size_t)bh * T_SEQ * DHEAD;
  const u16* Vp = Vtg + (size_t)bh * DHEAD * T_SEQ;

  // stage one 64x64 K tile + V^T tile into slot T&1 (256 thr x 2 gld16 each)
  auto stage_tile = [&](int T) {
    if (T > qt) return;
    const int slot = T & 1;
#pragma unroll
    for (int i = 0; i < 2; i++) {
      int c = i * 256 + tid;
      int r = c >> 3;
      int sw = ((c & 7) ^ (r & 7)) << 3;  // pre-swizzled global granule
      gld16(&Kp[(size_t)(T * 64 + r) * DHEAD + sw],
            &smem[slot * 4096 + c * 8]);
      gld16(&Vp[(size_t)r * T_SEQ + T * 64 + sw],
            &smem[8192 + slot * 4096 + c * 8]);
    }
  };

  const int qg = qb + wg * 32 + l31;  // this lane's global q row
  short8 qf[4];                        // Q B-frags: k = ks*16 + h*8 + {0..7}
#pragma unroll
  for (int ks = 0; ks < 4; ks++)
    qf[ks] = *(const short8*)&Qp[(size_t)qg * DHEAD + ks * 16 + h * 8];

  float mst = NEG_BIG, lst = 0.f;
  f32x16 oa0 = (f32x16)0.f, oa1 = (f32x16)0.f;  // O^T d-tiles 0/1 (col=q)

  const int Smax = (qt + 2) >> 1;  // ceil((qt+1)/2)
  for (int s = 0; s < Smax; s++) {
    __syncthreads();  // prior super-iter's slot readers done
    stage_tile(2 * s);
    stage_tile(2 * s + 1);
    __syncthreads();  // DMA drained (vmcnt0 before barrier)

    const int T = 2 * s + g;
    if (T <= qt) {
      const u16* Kc = &smem[g * 4096];
      const u16* Vc = &smem[8192 + g * 4096];

#pragma unroll
      for (int kvt2 = 0; kvt2 < 2; kvt2++) {  // 32-kv half-tiles
        f32x16 S = (f32x16)0.f;
        __builtin_amdgcn_s_setprio(1);
#pragma unroll
        for (int ks = 0; ks < 4; ks++) {
          short8 kf = *(const short8*)&Kc[(kvt2 * 32 + l31) * 64 +
                                          (((ks * 2 + h) ^ rsw) << 3)];
          S = MFMA32(kf, qf[ks], S);
        }
        __builtin_amdgcn_s_setprio(0);

        if (T == qt) {  // causal mask (diagonal tile only)
          const int kvb2 = T * 64 + kvt2 * 32 + 4 * h;
#pragma unroll
          for (int r = 0; r < 16; r++) {
            int kv = kvb2 + (r & 3) + 8 * (r >> 2);
            if (kv > qg) S[r] = NEG_BIG;
          }
        }

        // online softmax over this 32-kv half (R8-proven shfl_xor reduce)
        float mx = NEG_BIG;
#pragma unroll
        for (int r = 0; r < 16; r += 4)
          mx = fmaxf(mx,
                     fmaxf(fmaxf(S[r], S[r + 1]), fmaxf(S[r + 2], S[r + 3])));
        mx = fmaxf(mx, __shfl_xor(mx, 32));
        if (!__all(mx <= mst + RESCALE_THR)) {  // T13 defer-max
          float mn = fmaxf(mst, mx);
          float corr = EXP2(mst - mn);
          mst = mn;
          lst *= corr;
#pragma unroll
          for (int r = 0; r < 16; r++) {
            oa0[r] *= corr;
            oa1[r] *= corr;
          }
        }
        float ls = 0.f;
#pragma unroll
        for (int r = 0; r < 16; r++) {
          float pv = EXP2(S[r] - mst);
          S[r] = pv;
          ls += pv;
        }
        ls += __shfl_xor(ls, 32);
        lst += ls;

        // P -> B-frags in-register (R8-proven shfl_xor + select pattern)
#pragma unroll
        for (int ks2 = 0; ks2 < 2; ks2++) {
          unsigned P0 = pk2(S[8 * ks2 + 0], S[8 * ks2 + 1]);
          unsigned P1 = pk2(S[8 * ks2 + 2], S[8 * ks2 + 3]);
          unsigned P2 = pk2(S[8 * ks2 + 4], S[8 * ks2 + 5]);
          unsigned P3 = pk2(S[8 * ks2 + 6], S[8 * ks2 + 7]);
          unsigned R0 = __shfl_xor(P0, 32), R1 = __shfl_xor(P1, 32);
          unsigned R2 = __shfl_xor(P2, 32), R3 = __shfl_xor(P3, 32);
          uint4v fu;
          fu[0] = h ? R2 : P0;  // k j=0,1 (always sourced from half 0)
          fu[1] = h ? R3 : P1;  // k j=2,3
          fu[2] = h ? P2 : R0;  // k j=4,5 (always sourced from half 1)
          fu[3] = h ? P3 : R1;  // k j=6,7
          short8 pf = *(short8*)&fu;
          const int kgr = kvt2 * 4 + ks2 * 2 + h;  // V kv-granule of k-step
          __builtin_amdgcn_s_setprio(1);
          short8 vf0 = *(const short8*)&Vc[l31 * 64 + ((kgr ^ rsw) << 3)];
          oa0 = MFMA32(vf0, pf, oa0);
          short8 vf1 = *(const short8*)&Vc[(32 + l31) * 64 + ((kgr ^ rsw) << 3)];
          oa1 = MFMA32(vf1, pf, oa1);
          __builtin_amdgcn_s_setprio(0);
        }
      }
    }
  }

  // merge: group 1 publishes (O^T, m, l) into freed staging; group 0 combines.
  __syncthreads();  // last super-iter's readers done
  float* O1 = (float*)smem;          // [64 q][64 d] f32 = 16 KB (K region)
  float* ml = (float*)&smem[8192];   // m[64], l[64] (V region)
  const int q = wg * 32 + l31;
  if (g == 1) {
#pragma unroll
    for (int dt = 0; dt < 2; dt++)
#pragma unroll
      for (int t4 = 0; t4 < 4; t4++) {
        int gr = dt * 8 + t4 * 2 + h;  // 16B granule index within the q-row
        int swg = (gr & 8) | ((gr & 7) ^ (q & 7));
        f32x4 v;
#pragma unroll
        for (int j = 0; j < 4; j++) v[j] = dt ? oa1[t4 * 4 + j] : oa0[t4 * 4 + j];
        *(f32x4*)&O1[q * 64 + swg * 4] = v;
      }
    if (h == 0) {
      ml[q] = mst;
      ml[64 + q] = lst;
    }
  }
  __syncthreads();
  if (g == 0) {
    const float m1 = ml[q], l1 = ml[64 + q];
    const float M = fmaxf(mst, m1);
    const float c0 = EXP2(mst - M), c1 = EXP2(m1 - M);
    const float inv = 1.f / (c0 * lst + c1 * l1);
    size_t rowbase = ((size_t)(b * T_SEQ + qb + q)) * DMODEL + hh * DHEAD;
#pragma unroll
    for (int dt = 0; dt < 2; dt++)
#pragma unroll
      for (int t4 = 0; t4 < 4; t4++) {
        int gr = dt * 8 + t4 * 2 + h;
        int swg = (gr & 8) | ((gr & 7) ^ (q & 7));
        f32x4 o1 = *(const f32x4*)&O1[q * 64 + swg * 4];
        float a0 = (c0 * (dt ? oa1[t4 * 4 + 0] : oa0[t4 * 4 + 0]) + c1 * o1[0]) * inv;
        float a1 = (c0 * (dt ? oa1[t4 * 4 + 1] : oa0[t4 * 4 + 1]) + c1 * o1[1]) * inv;
        float a2 = (c0 * (dt ? oa1[t4 * 4 + 2] : oa0[t4 * 4 + 2]) + c1 * o1[2]) * inv;
        float a3 = (c0 * (dt ? oa1[t4 * 4 + 3] : oa0[t4 * 4 + 3]) + c1 * o1[3]) * inv;
        uint2v pk;
        pk[0] = (unsigned)f2bf(a0) | ((unsigned)f2bf(a1) << 16);
        pk[1] = (unsigned)f2bf(a2) | ((unsigned)f2bf(a3) << 16);
        *(uint2v*)&Ob[rowbase + dt * 32 + t4 * 8 + 4 * h] = pk;
      }
  }
}

// ---------------------------------------------------------------- out proj (bf16)
// 1-D grid 512, XCD-swizzled. BN=64 -> 2 blocks/CU.
__global__ __launch_bounds__(256) void gemm_out_bf(const u16* __restrict__ O,
                                                   const u16* __restrict__ Wo,
                                                   float* __restrict__ Out) {
  __shared__ __attribute__((aligned(16))) u16 As[2][128 * 32];
  __shared__ __attribute__((aligned(16))) u16 Bs[2][64 * 32];
  const int tid = threadIdx.x, lane = tid & 63, w = tid >> 6;
  const int wm = (w >> 1) * 64, wn = (w & 1) * 32;
  const int lrow = lane & 15;
  const int lk = (lane >> 4) << 3;
  const int lq = (lane >> 4) << 2;

  const int id = blockIdx.x;            // 0..511
  const int xcd = id & 7, r8 = id >> 3; // 0..63
  const int xo = r8 & 3, y = r8 >> 2;   // y: 0..15
  const int mBase = (xcd * 4 + xo) * 128, nBase = y * 64;

  f32x4 acc[4][2];
#pragma unroll
  for (int mi = 0; mi < 4; mi++)
#pragma unroll
    for (int ni = 0; ni < 2; ni++) acc[mi][ni] = (f32x4)0.0f;

  auto stage = [&](int buf, int k0) {
#pragma unroll
    for (int i = 0; i < 2; i++) {
      int c = i * 256 + tid;
      int r = c >> 2, kk = (c & 3) << 3;
      gld16(&O[(size_t)(mBase + r) * 1024 + k0 + kk], &As[buf][c * 8]);
    }
    int r = tid >> 2, kk = (tid & 3) << 3;
    gld16(&Wo[(size_t)(nBase + r) * 1024 + k0 + kk], &Bs[buf][tid * 8]);
  };

  stage(0, 0);
  __syncthreads();
  int cur = 0;
  for (int k0 = 0; k0 < 1024; k0 += 32) {
    if (k0 + 32 < 1024) stage(cur ^ 1, k0 + 32);
    short8 af[4], bf[2];
#pragma unroll
    for (int mi = 0; mi < 4; mi++)
      af[mi] = *(const short8*)&As[cur][(wm + mi * 16 + lrow) * 32 + lk];
#pragma unroll
    for (int ni = 0; ni < 2; ni++)
      bf[ni] = *(const short8*)&Bs[cur][(wn + ni * 16 + lrow) * 32 + lk];
#pragma unroll
    for (int mi = 0; mi < 4; mi++)
#pragma unroll
      for (int ni = 0; ni < 2; ni++)
        acc[mi][ni] = MFMA_BF16(af[mi], bf[ni], acc[mi][ni]);
    __syncthreads();
    cur ^= 1;
  }
#pragma unroll
  for (int mi = 0; mi < 4; mi++)
#pragma unroll
    for (int r = 0; r < 4; r++) {
      int m = mBase + wm + mi * 16 + lq + r;
#pragma unroll
      for (int ni = 0; ni < 2; ni++)
        Out[(size_t)m * DMODEL + nBase + wn + ni * 16 + lrow] = acc[mi][ni][r];
    }
}

// ---------------------------------------------------------------- launch
extern "C" void kernel_launch(void* const* d_in, const int* in_sizes, int n_in,
                              void* d_out, int out_size, void* d_ws,
                              size_t ws_size, hipStream_t stream) {
  const float* x = (const float*)d_in[0];
  const float* Wq = (const float*)d_in[1];
  const float* Wk = (const float*)d_in[2];
  const float* Wv = (const float*)d_in[3];
  const float* Wo = (const float*)d_in[4];
  float* out = (float*)d_out;

  u16* xh = (u16*)d_ws;      // 4M elems
  u16* wqh = xh + 4194304;   // 1M each
  u16* wkh = wqh + 1048576;
  u16* wvh = wkh + 1048576;
  u16* woh = wvh + 1048576;
  u16* Q = woh + 1048576;    // 4M each; V stored transposed (b,h,d,t)
  u16* K = Q + 4194304;
  u16* V = K + 4194304;
  u16* O = V + 4194304;      // total 48 MB

  cvt_all<<<dim3(4096), 256, 0, stream>>>(x, Wq, Wk, Wv, Wo, xh, wqh, wkh, wvh, woh);
  gemm_qkv<<<dim3(768), 256, 0, stream>>>(xh, wqh, wkh, wvh, Q, K, V);
  attn_q64<<<dim3(1024), 256, 0, stream>>>(Q, K, V, O);
  gemm_out_bf<<<dim3(512), 256, 0, stream>>>(O, woh, out);
}

// Round 11
// 167.890 us; speedup vs baseline: 1.0567x; 1.0567x over previous
//
#include <hip/hip_runtime.h>
#include <hip/hip_bf16.h>

typedef __attribute__((ext_vector_type(8))) short short8;
typedef __attribute__((ext_vector_type(4))) float f32x4;
typedef __attribute__((ext_vector_type(16))) float f32x16;
typedef __attribute__((ext_vector_type(2))) unsigned int uint2v;
typedef __attribute__((ext_vector_type(4))) unsigned int uint4v;
typedef unsigned short u16;

#define MFMA_BF16(a, b, c) __builtin_amdgcn_mfma_f32_16x16x32_bf16(a, b, c, 0, 0, 0)
#define MFMA32(a, b, c) __builtin_amdgcn_mfma_f32_32x32x16_bf16(a, b, c, 0, 0, 0)

#define T_SEQ 2048
#define DMODEL 1024
#define NHEADS 16
#define DHEAD 64
#define NEG_BIG (-30000.0f)
#define QSCALE 0.1803368801111f  // 0.125 * log2(e): softmax in exp2 domain
#define RESCALE_THR 8.0f         // defer-max threshold (exp2 domain): P <= 2^8

#if __has_builtin(__builtin_amdgcn_exp2f)
#define EXP2(x) __builtin_amdgcn_exp2f(x)
#else
#define EXP2(x) exp2f(x)
#endif

__device__ __forceinline__ unsigned bfr(unsigned u) {
  return (u + 0x7fffu + ((u >> 16) & 1u)) >> 16;
}
__device__ __forceinline__ uint4v ld8bf(const float* __restrict__ p) {
  const uint4v a = *(const uint4v*)p;
  const uint4v b = *(const uint4v*)(p + 4);
  uint4v r;
  r[0] = bfr(a[0]) | (bfr(a[1]) << 16);
  r[1] = bfr(a[2]) | (bfr(a[3]) << 16);
  r[2] = bfr(b[0]) | (bfr(b[1]) << 16);
  r[3] = bfr(b[2]) | (bfr(b[3]) << 16);
  return r;
}
__device__ __forceinline__ u16 f2bf(float f) {
  unsigned u = __float_as_uint(f);
  u += 0x7fffu + ((u >> 16) & 1u);
  return (u16)(u >> 16);
}
// packed bf16 truncation (P in [0,2^8], rel err < 0.4%)
__device__ __forceinline__ unsigned pk2(float a, float b) {
  return (__float_as_uint(a) >> 16) | (__float_as_uint(b) & 0xffff0000u);
}
// async global->LDS DMA, 16B per lane; lds dest must be uniform-base + lane*16
__device__ __forceinline__ void gld16(const u16* g, u16* l) {
  __builtin_amdgcn_global_load_lds(
      (const __attribute__((address_space(1))) unsigned int*)g,
      (__attribute__((address_space(3))) unsigned int*)l, 16, 0, 0);
}

// ---------------------------------------------------------------- cvt fp32->bf16
__global__ __launch_bounds__(256) void cvt_all(
    const float* __restrict__ x, const float* __restrict__ wq,
    const float* __restrict__ wk, const float* __restrict__ wv,
    const float* __restrict__ wo, u16* __restrict__ xh, u16* __restrict__ wqh,
    u16* __restrict__ wkh, u16* __restrict__ wvh, u16* __restrict__ woh) {
  int bi = blockIdx.x;
  const float* s;
  u16* d;
  size_t base;
  if (bi < 2048) {
    s = x; d = xh; base = (size_t)bi * 2048;
  } else {
    int k = (bi - 2048) >> 9;
    int r = (bi - 2048) & 511;
    s = (k == 0) ? wq : (k == 1) ? wk : (k == 2) ? wv : wo;
    d = (k == 0) ? wqh : (k == 1) ? wkh : (k == 2) ? wvh : woh;
    base = (size_t)r * 2048;
  }
  size_t i = base + (size_t)threadIdx.x * 8;
  *(uint4v*)&d[i] = ld8bf(&s[i]);
}

// ---------------------------------------------------------------- QKV proj (bf16)
// 1-D grid 768, XCD-swizzled (id&7 = XCD, x-chunk of 4 innermost). z=0 Q
// (pre-scaled), z=1 K -> (b,h,t,d); z=2 V -> TRANSPOSED (b,h,d,t).
// R11: ALL epilogues now per-wave LDS-transpose -> 16B coalesced stores.
// Previously z=0/1 wrote 64 scalar 2B scatter stores/lane (d = ni*16+lrow is
// lane-strided, unvectorizable in-lane) — the prime suspect for the opaque
// non-attn time. The z=2 (V) TT path was proven in R6.
__global__ __launch_bounds__(256) void gemm_qkv(
    const u16* __restrict__ X, const u16* __restrict__ Wq,
    const u16* __restrict__ Wk, const u16* __restrict__ Wv,
    u16* __restrict__ Qo, u16* __restrict__ Ko, u16* __restrict__ Vo) {
  __shared__ __attribute__((aligned(16))) u16 sm[16384];  // A dbuf | B dbuf; reused as TT
  const int tid = threadIdx.x, lane = tid & 63, w = tid >> 6;
  const int wm = (w >> 1) * 64, wn = (w & 1) * 64;
  const int lrow = lane & 15;
  const int lk = (lane >> 4) << 3;
  const int lq = (lane >> 4) << 2;

  const int id = blockIdx.x;        // 0..767
  const int xcd = id & 7, r8 = id >> 3;   // r8: 0..95
  const int xo = r8 & 3, yz = r8 >> 2;    // yz: 0..23
  const int y = yz & 7, z = yz >> 3;      // y: 0..7, z: 0..2
  const int mBase = (xcd * 4 + xo) * 128, nBase = y * 128;

  const u16* Bt = (z == 0) ? Wq : (z == 1) ? Wk : Wv;
  u16* D = (z == 0) ? Qo : (z == 1) ? Ko : Vo;
  const float scale = (z == 0) ? QSCALE : 1.0f;

  f32x4 acc[4][4];
#pragma unroll
  for (int mi = 0; mi < 4; mi++)
#pragma unroll
    for (int ni = 0; ni < 4; ni++) acc[mi][ni] = (f32x4)0.0f;

  auto stage = [&](int buf, int k0) {
#pragma unroll
    for (int i = 0; i < 2; i++) {
      int c = i * 256 + tid;
      int r = c >> 2, kk = (c & 3) << 3;
      gld16(&X[(size_t)(mBase + r) * 1024 + k0 + kk], &sm[buf * 4096 + c * 8]);
      gld16(&Bt[(size_t)(nBase + r) * 1024 + k0 + kk],
            &sm[8192 + buf * 4096 + c * 8]);
    }
  };

  stage(0, 0);
  __syncthreads();
  int cur = 0;
  for (int k0 = 0; k0 < 1024; k0 += 32) {
    if (k0 + 32 < 1024) stage(cur ^ 1, k0 + 32);
    short8 af[4], bf[4];
#pragma unroll
    for (int mi = 0; mi < 4; mi++)
      af[mi] = *(const short8*)&sm[cur * 4096 + (wm + mi * 16 + lrow) * 32 + lk];
#pragma unroll
    for (int ni = 0; ni < 4; ni++)
      bf[ni] =
          *(const short8*)&sm[8192 + cur * 4096 + (wn + ni * 16 + lrow) * 32 + lk];
#pragma unroll
    for (int mi = 0; mi < 4; mi++)
#pragma unroll
      for (int ni = 0; ni < 4; ni++)
        acc[mi][ni] = MFMA_BF16(af[mi], bf[ni], acc[mi][ni]);
    __syncthreads();  // drains vmcnt (next tile landed) + lgkm
    cur ^= 1;
  }

  // Epilogue: per-wave 64x64 LDS transpose (XOR-swizzled granules,
  // wave-private region -> no barrier), then 16B coalesced global stores.
  u16* TT = &sm[w * 4096];
  const int b = (mBase + wm) >> 11;
  const int t0 = (mBase + wm) & 2047;
  const int h0 = (nBase + wn) >> 6;  // wave's n-range spans exactly one head
  if (z != 2) {
    // layout [t_loc][d_loc]: row = t (contiguous d per output row)
#pragma unroll
    for (int mi = 0; mi < 4; mi++)
#pragma unroll
      for (int r = 0; r < 4; r++) {
        int t_loc = mi * 16 + lq + r;
#pragma unroll
        for (int ni = 0; ni < 4; ni++) {
          int d_loc = ni * 16 + lrow;
          TT[t_loc * 64 + ((((d_loc >> 3) ^ (t_loc & 7)) << 3) | (d_loc & 7))] =
              f2bf(acc[mi][ni][r] * scale);
        }
      }
#pragma unroll
    for (int it = 0; it < 8; it++) {
      int row = it * 8 + (lane >> 3);  // t_loc
      int ch = lane & 7;
      short8 v = *(const short8*)&TT[row * 64 + ((ch ^ (row & 7)) << 3)];
      *(uint4v*)&D[(((size_t)(b * NHEADS + h0)) * T_SEQ + t0 + row) * DHEAD +
                   ch * 8] = *(const uint4v*)&v;
    }
  } else {
    // V: layout [d_loc][t_loc]: row = d (contiguous t per output row)
#pragma unroll
    for (int mi = 0; mi < 4; mi++)
#pragma unroll
      for (int r = 0; r < 4; r++) {
        int t_loc = mi * 16 + lq + r;
#pragma unroll
        for (int ni = 0; ni < 4; ni++) {
          int d_loc = ni * 16 + lrow;
          TT[d_loc * 64 + ((((t_loc >> 3) ^ (d_loc & 7)) << 3) | (t_loc & 7))] =
              f2bf(acc[mi][ni][r]);
        }
      }
#pragma unroll
    for (int it = 0; it < 8; it++) {
      int d_loc = it * 8 + (lane >> 3);
      int ch = lane & 7;
      short8 v = *(const short8*)&TT[d_loc * 64 + ((ch ^ (d_loc & 7)) << 3)];
      int dd = (wn + d_loc) & 63;
      *(uint4v*)&D[(((size_t)((b * NHEADS + h0) * DHEAD + dd)) * T_SEQ) + t0 +
                   ch * 8] = *(const uint4v*)&v;
    }
  }
}

// ---------------------------------------------------------------- attention
// R10-verified attn (kept): q-tile 64, 256 thr = 2 kv-parity groups x 2
// waves, grid 1024; XCD-clustered decode (FETCH 123->12.4MB proven); 32x32
// MFMA with in-register P redistribution (shfl_xor pattern, R8/R10-proven);
// exact flash-merge via freed staging LDS. Per-tile serial cost ~3400cy has
// been invariant across 5 structures -> latency floor; parked at ~45.7us.
__global__ __launch_bounds__(256, 4) void attn_q64(
    const u16* __restrict__ Qg, const u16* __restrict__ Kg,
    const u16* __restrict__ Vtg, u16* __restrict__ Ob) {
  __shared__ __attribute__((aligned(16))) u16 smem[16384];  // 32768 B

  const int tid = threadIdx.x;
  const int w = tid >> 6, lane = tid & 63;
  const int g = w >> 1;             // kv-parity group 0/1
  const int wg = w & 1;             // q 32-slice within the 64-q tile
  const int l31 = lane & 31, h = lane >> 5;
  const int rsw = l31 & 7;          // swizzle key (= row&7)

  const int id = blockIdx.x;        // 0..1023
  const int seg = id >> 8;          // 0..3
  const int xcd = id & 7;
  const int bsub = (id >> 3) & 3;
  const int qv = (id >> 5) & 7;
  const int qt = (seg & 1) ? (seg * 8 + 7 - qv) : (seg * 8 + qv);
  const int bh = xcd * 4 + bsub;
  const int b = bh >> 4, hh = bh & 15;
  const int qb = qt << 6;
  const u16* Qp = Qg + (size_t)bh * T_SEQ * DHEAD;
  const u16* Kp = Kg + (size_t)bh * T_SEQ * DHEAD;
  const u16* Vp = Vtg + (size_t)bh * DHEAD * T_SEQ;

  // stage one 64x64 K tile + V^T tile into slot T&1 (256 thr x 2 gld16 each)
  auto stage_tile = [&](int T) {
    if (T > qt) return;
    const int slot = T & 1;
#pragma unroll
    for (int i = 0; i < 2; i++) {
      int c = i * 256 + tid;
      int r = c >> 3;
      int sw = ((c & 7) ^ (r & 7)) << 3;  // pre-swizzled global granule
      gld16(&Kp[(size_t)(T * 64 + r) * DHEAD + sw],
            &smem[slot * 4096 + c * 8]);
      gld16(&Vp[(size_t)r * T_SEQ + T * 64 + sw],
            &smem[8192 + slot * 4096 + c * 8]);
    }
  };

  const int qg = qb + wg * 32 + l31;  // this lane's global q row
  short8 qf[4];                        // Q B-frags: k = ks*16 + h*8 + {0..7}
#pragma unroll
  for (int ks = 0; ks < 4; ks++)
    qf[ks] = *(const short8*)&Qp[(size_t)qg * DHEAD + ks * 16 + h * 8];

  float mst = NEG_BIG, lst = 0.f;
  f32x16 oa0 = (f32x16)0.f, oa1 = (f32x16)0.f;  // O^T d-tiles 0/1 (col=q)

  const int Smax = (qt + 2) >> 1;  // ceil((qt+1)/2)
  for (int s = 0; s < Smax; s++) {
    __syncthreads();  // prior super-iter's slot readers done
    stage_tile(2 * s);
    stage_tile(2 * s + 1);
    __syncthreads();  // DMA drained (vmcnt0 before barrier)

    const int T = 2 * s + g;
    if (T <= qt) {
      const u16* Kc = &smem[g * 4096];
      const u16* Vc = &smem[8192 + g * 4096];

#pragma unroll
      for (int kvt2 = 0; kvt2 < 2; kvt2++) {  // 32-kv half-tiles
        f32x16 S = (f32x16)0.f;
        __builtin_amdgcn_s_setprio(1);
#pragma unroll
        for (int ks = 0; ks < 4; ks++) {
          short8 kf = *(const short8*)&Kc[(kvt2 * 32 + l31) * 64 +
                                          (((ks * 2 + h) ^ rsw) << 3)];
          S = MFMA32(kf, qf[ks], S);
        }
        __builtin_amdgcn_s_setprio(0);

        if (T == qt) {  // causal mask (diagonal tile only)
          const int kvb2 = T * 64 + kvt2 * 32 + 4 * h;
#pragma unroll
          for (int r = 0; r < 16; r++) {
            int kv = kvb2 + (r & 3) + 8 * (r >> 2);
            if (kv > qg) S[r] = NEG_BIG;
          }
        }

        // online softmax over this 32-kv half (R8-proven shfl_xor reduce)
        float mx = NEG_BIG;
#pragma unroll
        for (int r = 0; r < 16; r += 4)
          mx = fmaxf(mx,
                     fmaxf(fmaxf(S[r], S[r + 1]), fmaxf(S[r + 2], S[r + 3])));
        mx = fmaxf(mx, __shfl_xor(mx, 32));
        if (!__all(mx <= mst + RESCALE_THR)) {  // T13 defer-max
          float mn = fmaxf(mst, mx);
          float corr = EXP2(mst - mn);
          mst = mn;
          lst *= corr;
#pragma unroll
          for (int r = 0; r < 16; r++) {
            oa0[r] *= corr;
            oa1[r] *= corr;
          }
        }
        float ls = 0.f;
#pragma unroll
        for (int r = 0; r < 16; r++) {
          float pv = EXP2(S[r] - mst);
          S[r] = pv;
          ls += pv;
        }
        ls += __shfl_xor(ls, 32);
        lst += ls;

        // P -> B-frags in-register (R8-proven shfl_xor + select pattern)
#pragma unroll
        for (int ks2 = 0; ks2 < 2; ks2++) {
          unsigned P0 = pk2(S[8 * ks2 + 0], S[8 * ks2 + 1]);
          unsigned P1 = pk2(S[8 * ks2 + 2], S[8 * ks2 + 3]);
          unsigned P2 = pk2(S[8 * ks2 + 4], S[8 * ks2 + 5]);
          unsigned P3 = pk2(S[8 * ks2 + 6], S[8 * ks2 + 7]);
          unsigned R0 = __shfl_xor(P0, 32), R1 = __shfl_xor(P1, 32);
          unsigned R2 = __shfl_xor(P2, 32), R3 = __shfl_xor(P3, 32);
          uint4v fu;
          fu[0] = h ? R2 : P0;  // k j=0,1 (always sourced from half 0)
          fu[1] = h ? R3 : P1;  // k j=2,3
          fu[2] = h ? P2 : R0;  // k j=4,5 (always sourced from half 1)
          fu[3] = h ? P3 : R1;  // k j=6,7
          short8 pf = *(short8*)&fu;
          const int kgr = kvt2 * 4 + ks2 * 2 + h;  // V kv-granule of k-step
          __builtin_amdgcn_s_setprio(1);
          short8 vf0 = *(const short8*)&Vc[l31 * 64 + ((kgr ^ rsw) << 3)];
          oa0 = MFMA32(vf0, pf, oa0);
          short8 vf1 = *(const short8*)&Vc[(32 + l31) * 64 + ((kgr ^ rsw) << 3)];
          oa1 = MFMA32(vf1, pf, oa1);
          __builtin_amdgcn_s_setprio(0);
        }
      }
    }
  }

  // merge: group 1 publishes (O^T, m, l) into freed staging; group 0 combines.
  __syncthreads();  // last super-iter's readers done
  float* O1 = (float*)smem;          // [64 q][64 d] f32 = 16 KB (K region)
  float* ml = (float*)&smem[8192];   // m[64], l[64] (V region)
  const int q = wg * 32 + l31;
  if (g == 1) {
#pragma unroll
    for (int dt = 0; dt < 2; dt++)
#pragma unroll
      for (int t4 = 0; t4 < 4; t4++) {
        int gr = dt * 8 + t4 * 2 + h;  // 16B granule index within the q-row
        int swg = (gr & 8) | ((gr & 7) ^ (q & 7));
        f32x4 v;
#pragma unroll
        for (int j = 0; j < 4; j++) v[j] = dt ? oa1[t4 * 4 + j] : oa0[t4 * 4 + j];
        *(f32x4*)&O1[q * 64 + swg * 4] = v;
      }
    if (h == 0) {
      ml[q] = mst;
      ml[64 + q] = lst;
    }
  }
  __syncthreads();
  if (g == 0) {
    const float m1 = ml[q], l1 = ml[64 + q];
    const float M = fmaxf(mst, m1);
    const float c0 = EXP2(mst - M), c1 = EXP2(m1 - M);
    const float inv = 1.f / (c0 * lst + c1 * l1);
    size_t rowbase = ((size_t)(b * T_SEQ + qb + q)) * DMODEL + hh * DHEAD;
#pragma unroll
    for (int dt = 0; dt < 2; dt++)
#pragma unroll
      for (int t4 = 0; t4 < 4; t4++) {
        int gr = dt * 8 + t4 * 2 + h;
        int swg = (gr & 8) | ((gr & 7) ^ (q & 7));
        f32x4 o1 = *(const f32x4*)&O1[q * 64 + swg * 4];
        float a0 = (c0 * (dt ? oa1[t4 * 4 + 0] : oa0[t4 * 4 + 0]) + c1 * o1[0]) * inv;
        float a1 = (c0 * (dt ? oa1[t4 * 4 + 1] : oa0[t4 * 4 + 1]) + c1 * o1[1]) * inv;
        float a2 = (c0 * (dt ? oa1[t4 * 4 + 2] : oa0[t4 * 4 + 2]) + c1 * o1[2]) * inv;
        float a3 = (c0 * (dt ? oa1[t4 * 4 + 3] : oa0[t4 * 4 + 3]) + c1 * o1[3]) * inv;
        uint2v pk;
        pk[0] = (unsigned)f2bf(a0) | ((unsigned)f2bf(a1) << 16);
        pk[1] = (unsigned)f2bf(a2) | ((unsigned)f2bf(a3) << 16);
        *(uint2v*)&Ob[rowbase + dt * 32 + t4 * 8 + 4 * h] = pk;
      }
  }
}

// ---------------------------------------------------------------- out proj (bf16)
// 1-D grid 512, XCD-swizzled. BN=64 -> 2 blocks/CU. R11: f32 epilogue via
// per-wave 64x32 LDS transpose -> 16B fully-coalesced stores (was 8 dword
// stores in 64B fragments). LDS grown to 32KB (still 2 blocks/CU).
__global__ __launch_bounds__(256) void gemm_out_bf(const u16* __restrict__ O,
                                                   const u16* __restrict__ Wo,
                                                   float* __restrict__ Out) {
  __shared__ __attribute__((aligned(16))) u16 sm[16384];  // 32KB: A|B stage, TT epilogue
  const int tid = threadIdx.x, lane = tid & 63, w = tid >> 6;
  const int wm = (w >> 1) * 64, wn = (w & 1) * 32;
  const int lrow = lane & 15;
  const int lk = (lane >> 4) << 3;
  const int lq = (lane >> 4) << 2;

  const int id = blockIdx.x;            // 0..511
  const int xcd = id & 7, r8 = id >> 3; // 0..63
  const int xo = r8 & 3, y = r8 >> 2;   // y: 0..15
  const int mBase = (xcd * 4 + xo) * 128, nBase = y * 64;

  f32x4 acc[4][2];
#pragma unroll
  for (int mi = 0; mi < 4; mi++)
#pragma unroll
    for (int ni = 0; ni < 2; ni++) acc[mi][ni] = (f32x4)0.0f;

  // A dbuf at [0,8192) u16; B dbuf at [8192,12288) u16
  auto stage = [&](int buf, int k0) {
#pragma unroll
    for (int i = 0; i < 2; i++) {
      int c = i * 256 + tid;
      int r = c >> 2, kk = (c & 3) << 3;
      gld16(&O[(size_t)(mBase + r) * 1024 + k0 + kk],
            &sm[buf * 4096 + c * 8]);
    }
    int r = tid >> 2, kk = (tid & 3) << 3;
    gld16(&Wo[(size_t)(nBase + r) * 1024 + k0 + kk],
          &sm[8192 + buf * 2048 + tid * 8]);
  };

  stage(0, 0);
  __syncthreads();
  int cur = 0;
  for (int k0 = 0; k0 < 1024; k0 += 32) {
    if (k0 + 32 < 1024) stage(cur ^ 1, k0 + 32);
    short8 af[4], bf[2];
#pragma unroll
    for (int mi = 0; mi < 4; mi++)
      af[mi] = *(const short8*)&sm[cur * 4096 + (wm + mi * 16 + lrow) * 32 + lk];
#pragma unroll
    for (int ni = 0; ni < 2; ni++)
      bf[ni] = *(const short8*)&sm[8192 + cur * 2048 +
                                   (wn + ni * 16 + lrow) * 32 + lk];
#pragma unroll
    for (int mi = 0; mi < 4; mi++)
#pragma unroll
      for (int ni = 0; ni < 2; ni++)
        acc[mi][ni] = MFMA_BF16(af[mi], bf[ni], acc[mi][ni]);
    __syncthreads();
    cur ^= 1;
  }

  // Epilogue: per-wave 64(m) x 32(n) f32 transpose in LDS, then coalesced
  // 16B stores (8 lanes cover one 128B output row-segment).
  float* TT = (float*)&sm[w * 4096];  // 8KB per wave, wave-private
#pragma unroll
  for (int mi = 0; mi < 4; mi++)
#pragma unroll
    for (int r = 0; r < 4; r++) {
      int row = mi * 16 + lq + r;  // m_loc
#pragma unroll
      for (int ni = 0; ni < 2; ni++) {
        int col = ni * 16 + lrow;  // n_loc
        TT[row * 32 + ((((col >> 2) ^ (row & 7)) & 7) << 2) + (col & 3)] =
            acc[mi][ni][r];
      }
    }
#pragma unroll
  for (int it = 0; it < 8; it++) {
    int row = it * 8 + (lane >> 3);
    int ch = lane & 7;
    f32x4 v = *(const f32x4*)&TT[row * 32 + ((ch ^ (row & 7)) << 2)];
    *(f32x4*)&Out[(size_t)(mBase + wm + row) * DMODEL + nBase + wn + ch * 4] = v;
  }
}

// ---------------------------------------------------------------- launch
extern "C" void kernel_launch(void* const* d_in, const int* in_sizes, int n_in,
                              void* d_out, int out_size, void* d_ws,
                              size_t ws_size, hipStream_t stream) {
  const float* x = (const float*)d_in[0];
  const float* Wq = (const float*)d_in[1];
  const float* Wk = (const float*)d_in[2];
  const float* Wv = (const float*)d_in[3];
  const float* Wo = (const float*)d_in[4];
  float* out = (float*)d_out;

  u16* xh = (u16*)d_ws;      // 4M elems
  u16* wqh = xh + 4194304;   // 1M each
  u16* wkh = wqh + 1048576;
  u16* wvh = wkh + 1048576;
  u16* woh = wvh + 1048576;
  u16* Q = woh + 1048576;    // 4M each; V stored transposed (b,h,d,t)
  u16* K = Q + 4194304;
  u16* V = K + 4194304;
  u16* O = V + 4194304;      // total 48 MB

  cvt_all<<<dim3(4096), 256, 0, stream>>>(x, Wq, Wk, Wv, Wo, xh, wqh, wkh, wvh, woh);
  gemm_qkv<<<dim3(768), 256, 0, stream>>>(xh, wqh, wkh, wvh, Q, K, V);
  attn_q64<<<dim3(1024), 256, 0, stream>>>(Q, K, V, O);
  gemm_out_bf<<<dim3(512), 256, 0, stream>>>(O, woh, out);
}